// Round 7
// baseline (263.120 us; speedup 1.0000x reference)
//
#include <hip/hip_runtime.h>
#include <hip/hip_fp16.h>

#define N_NODES 50000
#define N_EDGES 800000
#define DIM 128
#define LAYERS 4
#define SLOT 48           // padded slots per node; 4B/slot -> node region = 192B = 3 lines
#define EPB 16            // edges scanned per thread in bucket (N_EDGES % EPB == 0)

#define PACK_BLOCKS 782      // ceil(800000/(256*4))
#define WT_BLOCKS 256        // LAYERS*DIM*DIM/256
#define INIT_BLOCKS 3125     // N_NODES*DIM/8/256 (8 elems -> 8 fp8 bytes per thread)
#define CNT_BLOCKS 196       // ceil(50000/256) -- cnt zeroing folded into prep1
#define BUCKET_BLOCKS 1568   // ceil(800000/(256*16)) * 8 = 196*8

typedef __attribute__((ext_vector_type(8))) _Float16 half8;
typedef __attribute__((ext_vector_type(4))) float float4v;
typedef __attribute__((ext_vector_type(2))) float float2v;
typedef __attribute__((ext_vector_type(8))) unsigned short ushort8;

// pack: src (u16) | w (fp16) << 16
__device__ __forceinline__ int pack_edge(int s, float w) {
    return (int)(((unsigned)__half_as_ushort(__float2half(w)) << 16) | (unsigned)(s & 0xFFFF));
}

// decode 8 fp8 (e4m3) packed in uint2 -> 8 floats
__device__ __forceinline__ void fp8x8_to_f32(uint2 v, float* f) {
    float2v a = __builtin_amdgcn_cvt_pk_f32_fp8(v.x, false);
    float2v b = __builtin_amdgcn_cvt_pk_f32_fp8(v.x, true);
    float2v c = __builtin_amdgcn_cvt_pk_f32_fp8(v.y, false);
    float2v d = __builtin_amdgcn_cvt_pk_f32_fp8(v.y, true);
    f[0] = a[0]; f[1] = a[1]; f[2] = b[0]; f[3] = b[1];
    f[4] = c[0]; f[5] = c[1]; f[6] = d[0]; f[7] = d[1];
}

// encode 8 floats -> 8 fp8 in uint2
__device__ __forceinline__ uint2 f32x8_to_fp8(const float* f) {
    unsigned lo = 0, hi = 0;
    lo = __builtin_amdgcn_cvt_pk_fp8_f32(f[0], f[1], lo, false);
    lo = __builtin_amdgcn_cvt_pk_fp8_f32(f[2], f[3], lo, true);
    hi = __builtin_amdgcn_cvt_pk_fp8_f32(f[4], f[5], hi, false);
    hi = __builtin_amdgcn_cvt_pk_fp8_f32(f[6], f[7], hi, true);
    return make_uint2(lo, hi);
}

// ---------------- prep1: edge compress + wt_prep + init + cnt-zero ---------
// blocks [0, PACK_BLOCKS): dst -> u16 (1.6MB), (src,w) -> packed int (3.2MB).
// blocks [+WT_BLOCKS): W fp32 [K][N] -> Wt fp16 [N][K].
// blocks [+INIT_BLOCKS): X0 = fp8(x) (8 elems/thread).
// blocks [+CNT_BLOCKS): cnt = 0 (replaces the hipMemsetAsync dispatch).
__global__ __launch_bounds__(256) void prep1_kernel(const int* __restrict__ src,
                                                    const int* __restrict__ dst,
                                                    const float* __restrict__ w,
                                                    unsigned short* __restrict__ dst16,
                                                    int* __restrict__ epk,
                                                    const float* __restrict__ W,
                                                    __half* __restrict__ Wt,
                                                    const float4* __restrict__ x,
                                                    uint2* __restrict__ xh0,
                                                    int* __restrict__ cnt) {
    int bid = blockIdx.x;
    int tid = threadIdx.x;
    if (bid < PACK_BLOCKS) {
        int e = (bid * 256 + tid) * 4;
        if (e >= N_EDGES) return;
        int4   d4 = *(const int4*)(dst + e);
        int4   s4 = *(const int4*)(src + e);
        float4 w4 = *(const float4*)(w + e);
        uint2 dd;
        dd.x = ((unsigned)d4.x & 0xFFFF) | ((unsigned)d4.y << 16);
        dd.y = ((unsigned)d4.z & 0xFFFF) | ((unsigned)d4.w << 16);
        *(uint2*)(dst16 + e) = dd;
        int4 pk = make_int4(pack_edge(s4.x, w4.x), pack_edge(s4.y, w4.y),
                            pack_edge(s4.z, w4.z), pack_edge(s4.w, w4.w));
        *(int4*)(epk + e) = pk;
    } else if (bid < PACK_BLOCKS + WT_BLOCKS) {
        int i = (bid - PACK_BLOCKS) * 256 + tid;   // < 65536 exact
        int l   = i >> 14;
        int rem = i & 16383;
        int k = rem >> 7;
        int n = rem & 127;
        Wt[(size_t)l * DIM * DIM + n * DIM + k] =
            __float2half(W[(size_t)l * DIM * DIM + k * DIM + n]);
    } else if (bid < PACK_BLOCKS + WT_BLOCKS + INIT_BLOCKS) {
        int i = (bid - PACK_BLOCKS - WT_BLOCKS) * 256 + tid;  // < 800000 exact
        float4 a = x[(size_t)i * 2];
        float4 b = x[(size_t)i * 2 + 1];
        float f[8] = { a.x, a.y, a.z, a.w, b.x, b.y, b.z, b.w };
        xh0[i] = f32x8_to_fp8(f);
    } else {
        int i = (bid - PACK_BLOCKS - WT_BLOCKS - INIT_BLOCKS) * 256 + tid;
        if (i < N_NODES) cnt[i] = 0;
    }
}

// ---------------- bucket: XCD-partitioned padded-bucket build ---------------
// plain (cached) loads: nt regressed (r1) -- the x8 replicated scan relies on
// L2/L3 absorption. EPB=16: 16 independent atomic chains per thread.
__device__ __forceinline__ void bucket_one(int d, int pk, int g,
                                           int* __restrict__ cnt,
                                           int* __restrict__ edge_buf) {
    if ((d & 7) == g) {
        int pos = atomicAdd(&cnt[d], 1);
        edge_buf[(size_t)d * SLOT + pos] = pk;
    }
}

__global__ __launch_bounds__(256) void bucket_kernel(const unsigned short* __restrict__ dst16,
                                                     const int* __restrict__ epk,
                                                     int* __restrict__ cnt,
                                                     int* __restrict__ edge_buf) {
    int g     = blockIdx.x & 7;
    int chunk = blockIdx.x >> 3;
    int base  = (chunk * 256 + threadIdx.x) * EPB;
    if (base >= N_EDGES) return;
    ushort8 d8a = *(const ushort8*)(dst16 + base);
    ushort8 d8b = *(const ushort8*)(dst16 + base + 8);
    int4 p0 = *(const int4*)(epk + base);
    int4 p1 = *(const int4*)(epk + base + 4);
    int4 p2 = *(const int4*)(epk + base + 8);
    int4 p3 = *(const int4*)(epk + base + 12);
    bucket_one(d8a[0], p0.x, g, cnt, edge_buf);
    bucket_one(d8a[1], p0.y, g, cnt, edge_buf);
    bucket_one(d8a[2], p0.z, g, cnt, edge_buf);
    bucket_one(d8a[3], p0.w, g, cnt, edge_buf);
    bucket_one(d8a[4], p1.x, g, cnt, edge_buf);
    bucket_one(d8a[5], p1.y, g, cnt, edge_buf);
    bucket_one(d8a[6], p1.z, g, cnt, edge_buf);
    bucket_one(d8a[7], p1.w, g, cnt, edge_buf);
    bucket_one(d8b[0], p2.x, g, cnt, edge_buf);
    bucket_one(d8b[1], p2.y, g, cnt, edge_buf);
    bucket_one(d8b[2], p2.z, g, cnt, edge_buf);
    bucket_one(d8b[3], p2.w, g, cnt, edge_buf);
    bucket_one(d8b[4], p3.x, g, cnt, edge_buf);
    bucket_one(d8b[5], p3.y, g, cnt, edge_buf);
    bucket_one(d8b[6], p3.z, g, cnt, edge_buf);
    bucket_one(d8b[7], p3.w, g, cnt, edge_buf);
}

// Process 16 edges (slots base..base+15, meta register m) for this lane's
// node. ALL 16 loads issue before any decode/FMA: 16 outstanding 8B loads
// per lane (vs 8 in the old batch8) -- the gather is concurrency-limited
// (r5: 2.4TB/s at 28 waves/CU x 8 outstanding / ~300cy), so widening the
// window is the lever. VGPR cost ~+28 accepted; NO launch_bounds cap (r4).
__device__ __forceinline__ void batch16(const uint2* __restrict__ x8,
                                        int m, int base, int cnt_r, int r, int c,
                                        float* accf, float& wsum) {
    uint2 v[16]; float wv[16];
    #pragma unroll
    for (int u = 0; u < 16; ++u) {
        int jj = base + u;
        int p  = __shfl(m, (r << 4) | (jj & 15), 64);
        bool live = (jj < cnt_r);
        wv[u] = live
                  ? __half2float(__ushort_as_half((unsigned short)((unsigned)p >> 16)))
                  : 0.f;
        uint2 vv = make_uint2(0u, 0u);
        if (live) vv = x8[(size_t)(p & 0xFFFF) * 16 + c];
        v[u] = vv;
    }
    #pragma unroll
    for (int u = 0; u < 16; ++u) {
        wsum += wv[u];
        float f[8];
        fp8x8_to_f32(v[u], f);
        #pragma unroll
        for (int t = 0; t < 8; ++t)
            accf[t] += wv[u] * f[t];
    }
}

// Fused layer: gather A = segsum(w * xin[src]) -> 16x128 fp16 tile in LDS ->
// MFMA A@W + win*b -> relu.
// FINAL=false: store layer output as fp8 to xout. NO hidden traffic.
// FINAL=true : full GPR combine, all-fp8 inputs:
//   hidden = t0*X0 + t1*X1 + t2*X2 + t3*X3 + t4*out   (xin == X3)
#define AP 136
template <bool FINAL>
__global__ __launch_bounds__(256) void layer_kernel(const uint2* __restrict__ xin8,
                                                    const int* __restrict__ cnt_arr,
                                                    const int* __restrict__ edge_buf,
                                                    const __half* __restrict__ Wt,
                                                    const float* __restrict__ bl,
                                                    uint2* __restrict__ xout,
                                                    float* __restrict__ hidden,
                                                    const float* __restrict__ temp,
                                                    const uint2* __restrict__ x0h,
                                                    const uint2* __restrict__ x1h,
                                                    const uint2* __restrict__ x2h) {
    __shared__ __half Ah[16][AP];
    __shared__ float winS[16];
    int tid  = threadIdx.x;
    int wave = tid >> 6;
    int lane = tid & 63;
    int r = lane >> 4;    // node subgroup 0..3
    int c = lane & 15;    // 8B chunk within fp8 row
    int node0  = blockIdx.x * 16 + wave * 4;
    int node_r = node0 + r;

    // upfront, independent: m0/m1 meta (slots 0-31) + cnt4. m2 (slots 32-47)
    // is needed by ~0.05% of waves -> load deferred into the rare branch.
    size_t mb = (size_t)node_r * SLOT;
    int m0 = edge_buf[mb + c];
    int m1 = edge_buf[mb + 16 + c];
    int4 c4 = *(const int4*)(cnt_arr + node0);

    int cnt_r = (r == 0) ? c4.x : (r == 1) ? c4.y : (r == 2) ? c4.z : c4.w;
    int maxc  = max(max(c4.x, c4.y), max(c4.z, c4.w));   // wave-uniform

    float accf[8];
    #pragma unroll
    for (int t = 0; t < 8; ++t) accf[t] = 0.f;
    float wsum = 0.f;

    batch16(xin8, m0, 0, cnt_r, r, c, accf, wsum);
    if (maxc > 16)
        batch16(xin8, m1, 16, cnt_r, r, c, accf, wsum);
    if (maxc > 32) {
        int m2 = edge_buf[mb + 32 + c];
        batch16(xin8, m2, 32, cnt_r, r, c, accf, wsum);
    }

    // A tile (fp32 acc -> fp16) into LDS; 16 rows x 128 cols
    union { __half2 hh[4]; float4 f4; } ua;
    ua.hh[0] = __floats2half2_rn(accf[0], accf[1]);
    ua.hh[1] = __floats2half2_rn(accf[2], accf[3]);
    ua.hh[2] = __floats2half2_rn(accf[4], accf[5]);
    ua.hh[3] = __floats2half2_rn(accf[6], accf[7]);
    int lr = wave * 4 + r;
    *(float4*)&Ah[lr][c * 8] = ua.f4;
    if (c == 0) winS[lr] = wsum;
    __syncthreads();

    // MFMA tail: wave computes rows 0..15 x cols [wave*32, wave*32+32)
    int am  = lane & 15;
    int ak8 = (lane >> 4) * 8;
    float4v acc0 = (float4v)(0.f), acc1 = (float4v)(0.f);
    #pragma unroll
    for (int kk = 0; kk < 4; ++kk) {
        int k0 = kk * 32 + ak8;
        half8 a  = *(const half8*)&Ah[am][k0];
        half8 b0 = *(const half8*)(Wt + (size_t)(wave * 32 + am) * DIM + k0);
        half8 b1 = *(const half8*)(Wt + (size_t)(wave * 32 + 16 + am) * DIM + k0);
        acc0 = __builtin_amdgcn_mfma_f32_16x16x32_f16(a, b0, acc0, 0, 0, 0);
        acc1 = __builtin_amdgcn_mfma_f32_16x16x32_f16(a, b1, acc1, 0, 0, 0);
    }
    __syncthreads();

    // epilogue: + win*b, relu, back to LDS fp16 for coalesced stores
    int q  = lane >> 4;
    int cc = lane & 15;
    {
        int col = wave * 32 + cc;
        float bv = bl[col];
        #pragma unroll
        for (int j = 0; j < 4; ++j) {
            int row = q * 4 + j;
            Ah[row][col] = __float2half(fmaxf(acc0[j] + winS[row] * bv, 0.f));
        }
        col = wave * 32 + 16 + cc;
        bv = bl[col];
        #pragma unroll
        for (int j = 0; j < 4; ++j) {
            int row = q * 4 + j;
            Ah[row][col] = __float2half(fmaxf(acc1[j] + winS[row] * bv, 0.f));
        }
    }
    __syncthreads();

    // 256 threads == 16 rows x 16 chunks
    int row = tid >> 4;
    int ch  = tid & 15;
    int gnode = blockIdx.x * 16 + row;
    half8 hv = *(const half8*)&Ah[row][ch * 8];
    size_t ro = (size_t)gnode * 16 + ch;

    if constexpr (!FINAL) {
        float f[8];
        #pragma unroll
        for (int t = 0; t < 8; ++t) f[t] = (float)hv[t];
        xout[ro] = f32x8_to_fp8(f);
    } else {
        float t0 = temp[0], t1 = temp[1], t2 = temp[2], t3 = temp[3], t4 = temp[4];
        uint2 u0 = x0h[ro], u1 = x1h[ro], u2 = x2h[ro], u3 = xin8[ro];
        float f0[8], f1[8], f2[8], f3[8];
        fp8x8_to_f32(u0, f0);
        fp8x8_to_f32(u1, f1);
        fp8x8_to_f32(u2, f2);
        fp8x8_to_f32(u3, f3);
        float out[8];
        #pragma unroll
        for (int t = 0; t < 8; ++t)
            out[t] = t0 * f0[t] + t1 * f1[t] + t2 * f2[t]
                   + t3 * f3[t] + t4 * (float)hv[t];
        size_t o = (size_t)gnode * DIM + ch * 8;
        *(float4*)(hidden + o)     = make_float4(out[0], out[1], out[2], out[3]);
        *(float4*)(hidden + o + 4) = make_float4(out[4], out[5], out[6], out[7]);
    }
}

extern "C" void kernel_launch(void* const* d_in, const int* in_sizes, int n_in,
                              void* d_out, int out_size, void* d_ws, size_t ws_size,
                              hipStream_t stream) {
    const float* x    = (const float*)d_in[0];
    const float* w    = (const float*)d_in[1];
    const int*   src  = (const int*)d_in[2];
    const int*   dst  = (const int*)d_in[3];
    const float* W    = (const float*)d_in[4];
    const float* b    = (const float*)d_in[5];
    const float* temp = (const float*)d_in[6];
    float* hidden = (float*)d_out;

    char* ws = (char*)d_ws;
    // 4 fp8 x buffers: init->X0, L1 X0->X1, L2 X1->X2, L3 X2->X3,
    // L4 gathers X3 and combines X0..X3 + its own output into hidden.
    uint2* X0 = (uint2*)ws;                  ws += (size_t)N_NODES * DIM;   // fp8: 1B/elem
    uint2* X1 = (uint2*)ws;                  ws += (size_t)N_NODES * DIM;
    uint2* X2 = (uint2*)ws;                  ws += (size_t)N_NODES * DIM;
    uint2* X3 = (uint2*)ws;                  ws += (size_t)N_NODES * DIM;
    __half* Wt = (__half*)ws;                ws += (size_t)LAYERS * DIM * DIM * sizeof(__half);
    int* cnt = (int*)ws;                     ws += (size_t)N_NODES * sizeof(int);
    int* edge_buf = (int*)ws;                ws += (size_t)(N_NODES * SLOT + 64) * sizeof(int);
    unsigned short* dst16 = (unsigned short*)ws;  ws += (size_t)N_EDGES * sizeof(unsigned short);
    int* epk = (int*)ws;                     ws += (size_t)N_EDGES * sizeof(int);

    prep1_kernel<<<PACK_BLOCKS + WT_BLOCKS + INIT_BLOCKS + CNT_BLOCKS, 256, 0, stream>>>(
        src, dst, w, dst16, epk, W, Wt, (const float4*)x, X0, cnt);
    bucket_kernel<<<BUCKET_BLOCKS, 256, 0, stream>>>(dst16, epk, cnt, edge_buf);

    const int layer_blocks = N_NODES / 16;   // 3125, exact
    layer_kernel<false><<<layer_blocks, 256, 0, stream>>>(
        X0, cnt, edge_buf, Wt + 0 * DIM * DIM, b + 0 * DIM,
        X1, hidden, temp, nullptr, nullptr, nullptr);
    layer_kernel<false><<<layer_blocks, 256, 0, stream>>>(
        X1, cnt, edge_buf, Wt + 1 * DIM * DIM, b + 1 * DIM,
        X2, hidden, temp, nullptr, nullptr, nullptr);
    layer_kernel<false><<<layer_blocks, 256, 0, stream>>>(
        X2, cnt, edge_buf, Wt + 2 * DIM * DIM, b + 2 * DIM,
        X3, hidden, temp, nullptr, nullptr, nullptr);
    layer_kernel<true><<<layer_blocks, 256, 0, stream>>>(
        X3, cnt, edge_buf, Wt + 3 * DIM * DIM, b + 3 * DIM,
        nullptr, hidden, temp, X0, X1, X2);
}

// Round 8
// 247.519 us; speedup vs baseline: 1.0630x; 1.0630x over previous
//
#include <hip/hip_runtime.h>
#include <hip/hip_fp16.h>

#define N_NODES 50000
#define N_EDGES 800000
#define DIM 128
#define LAYERS 4
#define SLOT 48           // padded slots per node; 4B/slot -> node region = 192B = 3 lines
#define EPB 8             // edges scanned per thread in bucket (N_EDGES % EPB == 0)

#define BUCKET_BLOCKS 3128   // ceil(800000/(256*8)) * 8 = 391*8
#define WT_BLOCKS 256        // LAYERS*DIM*DIM/256
#define INIT_BLOCKS 3125     // N_NODES*DIM/8/256 (8 elems -> 8 fp8 bytes per thread)

typedef __attribute__((ext_vector_type(8))) _Float16 half8;
typedef __attribute__((ext_vector_type(4))) float float4v;
typedef __attribute__((ext_vector_type(2))) float float2v;

// pack: src (u16) | w (fp16) << 16
__device__ __forceinline__ int pack_edge(int s, float w) {
    return (int)(((unsigned)__half_as_ushort(__float2half(w)) << 16) | (unsigned)(s & 0xFFFF));
}

// decode 8 fp8 (e4m3) packed in uint2 -> 8 floats
__device__ __forceinline__ void fp8x8_to_f32(uint2 v, float* f) {
    float2v a = __builtin_amdgcn_cvt_pk_f32_fp8(v.x, false);
    float2v b = __builtin_amdgcn_cvt_pk_f32_fp8(v.x, true);
    float2v c = __builtin_amdgcn_cvt_pk_f32_fp8(v.y, false);
    float2v d = __builtin_amdgcn_cvt_pk_f32_fp8(v.y, true);
    f[0] = a[0]; f[1] = a[1]; f[2] = b[0]; f[3] = b[1];
    f[4] = c[0]; f[5] = c[1]; f[6] = d[0]; f[7] = d[1];
}

// encode 8 floats -> 8 fp8 in uint2
__device__ __forceinline__ uint2 f32x8_to_fp8(const float* f) {
    unsigned lo = 0, hi = 0;
    lo = __builtin_amdgcn_cvt_pk_fp8_f32(f[0], f[1], lo, false);
    lo = __builtin_amdgcn_cvt_pk_fp8_f32(f[2], f[3], lo, true);
    hi = __builtin_amdgcn_cvt_pk_fp8_f32(f[4], f[5], hi, false);
    hi = __builtin_amdgcn_cvt_pk_fp8_f32(f[6], f[7], hi, true);
    return make_uint2(lo, hi);
}

__device__ __forceinline__ void bucket_one(int d, int s, float wv, int g,
                                           int* __restrict__ cnt,
                                           int* __restrict__ edge_buf) {
    if ((d & 7) == g) {
        int pos = atomicAdd(&cnt[d], 1);
        edge_buf[(size_t)d * SLOT + pos] = pack_edge(s, wv);
    }
}

// ---------------- fused prep: bucket + wt_prep + init, ONE dispatch --------
// r7 lesson: bucket is pinned at ~44us regardless of bytes (latency floor of
// 800K scattered atomic+store pairs; FETCH 19MB, BW 14%, VALU 3%). So: stop
// feeding it fewer bytes (pack pass deleted), instead HIDE it -- wt + fp8
// init run in the same dispatch and fill the machine inside bucket's latency
// shadow. cnt zeroed by hipMemsetAsync beforehand.
// blocks [0, BUCKET_BLOCKS): XCD-partitioned padded-bucket build, raw streams.
// blocks [+WT_BLOCKS): W fp32 [K][N] -> Wt fp16 [N][K].
// blocks [+INIT_BLOCKS): X0 = fp8(x) (8 elems/thread).
__global__ __launch_bounds__(256) void prep_kernel(const int* __restrict__ src,
                                                   const int* __restrict__ dst,
                                                   const float* __restrict__ w,
                                                   int* __restrict__ cnt,
                                                   int* __restrict__ edge_buf,
                                                   const float* __restrict__ W,
                                                   __half* __restrict__ Wt,
                                                   const float4* __restrict__ x,
                                                   uint2* __restrict__ xh0) {
    int bid = blockIdx.x;
    int tid = threadIdx.x;
    if (bid < BUCKET_BLOCKS) {
        int g     = bid & 7;
        int chunk = bid >> 3;
        int base  = (chunk * 256 + tid) * EPB;
        if (base >= N_EDGES) return;
        int4   d4a = *(const int4*)(dst + base);
        int4   d4b = *(const int4*)(dst + base + 4);
        int4   s4a = *(const int4*)(src + base);
        int4   s4b = *(const int4*)(src + base + 4);
        float4 w4a = *(const float4*)(w + base);
        float4 w4b = *(const float4*)(w + base + 4);
        bucket_one(d4a.x, s4a.x, w4a.x, g, cnt, edge_buf);
        bucket_one(d4a.y, s4a.y, w4a.y, g, cnt, edge_buf);
        bucket_one(d4a.z, s4a.z, w4a.z, g, cnt, edge_buf);
        bucket_one(d4a.w, s4a.w, w4a.w, g, cnt, edge_buf);
        bucket_one(d4b.x, s4b.x, w4b.x, g, cnt, edge_buf);
        bucket_one(d4b.y, s4b.y, w4b.y, g, cnt, edge_buf);
        bucket_one(d4b.z, s4b.z, w4b.z, g, cnt, edge_buf);
        bucket_one(d4b.w, s4b.w, w4b.w, g, cnt, edge_buf);
    } else if (bid < BUCKET_BLOCKS + WT_BLOCKS) {
        int i = (bid - BUCKET_BLOCKS) * 256 + tid;   // < 65536 exact
        int l   = i >> 14;
        int rem = i & 16383;
        int k = rem >> 7;
        int n = rem & 127;
        Wt[(size_t)l * DIM * DIM + n * DIM + k] =
            __float2half(W[(size_t)l * DIM * DIM + k * DIM + n]);
    } else {
        int i = (bid - BUCKET_BLOCKS - WT_BLOCKS) * 256 + tid;  // < 800000 exact
        float4 a = x[(size_t)i * 2];
        float4 b = x[(size_t)i * 2 + 1];
        float f[8] = { a.x, a.y, a.z, a.w, b.x, b.y, b.z, b.w };
        xh0[i] = f32x8_to_fp8(f);
    }
}

// Process 8 edges (slots base..base+7, meta register m) for this lane's node.
// batch8 (NOT 16: r7 showed the wider window costs VGPR 72->~104, waves
// 7->4/SIMD, and regressed ~13us). Dead slots: load exec-masked off.
__device__ __forceinline__ void batch8(const uint2* __restrict__ x8,
                                       int m, int base, int cnt_r, int r, int c,
                                       float* accf, float& wsum) {
    uint2 v[8]; float wv[8];
    #pragma unroll
    for (int u = 0; u < 8; ++u) {
        int jj = base + u;
        int p  = __shfl(m, (r << 4) | (jj & 15), 64);
        bool live = (jj < cnt_r);
        wv[u] = live
                  ? __half2float(__ushort_as_half((unsigned short)((unsigned)p >> 16)))
                  : 0.f;
        uint2 vv = make_uint2(0u, 0u);
        if (live) vv = x8[(size_t)(p & 0xFFFF) * 16 + c];
        v[u] = vv;
    }
    #pragma unroll
    for (int u = 0; u < 8; ++u) {
        wsum += wv[u];
        float f[8];
        fp8x8_to_f32(v[u], f);
        #pragma unroll
        for (int t = 0; t < 8; ++t)
            accf[t] += wv[u] * f[t];
    }
}

// Fused layer: gather A = segsum(w * xin[src]) -> 16x128 fp16 tile in LDS ->
// MFMA A@W + win*b -> relu.
// FINAL=false: store layer output as fp8 to xout. NO hidden traffic.
// FINAL=true : full GPR combine, all-fp8 inputs:
//   hidden = t0*X0 + t1*X1 + t2*X2 + t3*X3 + t4*out   (xin == X3)
// NOTE: plain __launch_bounds__(256). r4's (256,6) forced VGPR 68->40,
// spilled batch8 arrays (WRITE 12.5->218MB, 2.3x slower). Never cap.
#define AP 136
template <bool FINAL>
__global__ __launch_bounds__(256) void layer_kernel(const uint2* __restrict__ xin8,
                                                    const int* __restrict__ cnt_arr,
                                                    const int* __restrict__ edge_buf,
                                                    const __half* __restrict__ Wt,
                                                    const float* __restrict__ bl,
                                                    uint2* __restrict__ xout,
                                                    float* __restrict__ hidden,
                                                    const float* __restrict__ temp,
                                                    const uint2* __restrict__ x0h,
                                                    const uint2* __restrict__ x1h,
                                                    const uint2* __restrict__ x2h) {
    __shared__ __half Ah[16][AP];
    __shared__ float winS[16];
    int tid  = threadIdx.x;
    int wave = tid >> 6;
    int lane = tid & 63;
    int r = lane >> 4;    // node subgroup 0..3
    int c = lane & 15;    // 8B chunk within fp8 row
    int node0  = blockIdx.x * 16 + wave * 4;
    int node_r = node0 + r;

    // upfront, independent: m0/m1 meta (slots 0-31) + cnt4. m2 (slots 32-47)
    // is needed by ~0.05% of waves -> load deferred into the rare branch.
    size_t mb = (size_t)node_r * SLOT;
    int m0 = edge_buf[mb + c];
    int m1 = edge_buf[mb + 16 + c];
    int4 c4 = *(const int4*)(cnt_arr + node0);

    int cnt_r = (r == 0) ? c4.x : (r == 1) ? c4.y : (r == 2) ? c4.z : c4.w;
    int maxc  = max(max(c4.x, c4.y), max(c4.z, c4.w));   // wave-uniform

    float accf[8];
    #pragma unroll
    for (int t = 0; t < 8; ++t) accf[t] = 0.f;
    float wsum = 0.f;

    batch8(xin8, m0, 0, cnt_r, r, c, accf, wsum);
    batch8(xin8, m0, 8, cnt_r, r, c, accf, wsum);
    if (maxc > 16) {
        batch8(xin8, m1, 16, cnt_r, r, c, accf, wsum);
        batch8(xin8, m1, 24, cnt_r, r, c, accf, wsum);
    }
    if (maxc > 32) {
        int m2 = edge_buf[mb + 32 + c];
        batch8(xin8, m2, 32, cnt_r, r, c, accf, wsum);
        batch8(xin8, m2, 40, cnt_r, r, c, accf, wsum);
    }

    // A tile (fp32 acc -> fp16) into LDS; 16 rows x 128 cols
    union { __half2 hh[4]; float4 f4; } ua;
    ua.hh[0] = __floats2half2_rn(accf[0], accf[1]);
    ua.hh[1] = __floats2half2_rn(accf[2], accf[3]);
    ua.hh[2] = __floats2half2_rn(accf[4], accf[5]);
    ua.hh[3] = __floats2half2_rn(accf[6], accf[7]);
    int lr = wave * 4 + r;
    *(float4*)&Ah[lr][c * 8] = ua.f4;
    if (c == 0) winS[lr] = wsum;
    __syncthreads();

    // MFMA tail: wave computes rows 0..15 x cols [wave*32, wave*32+32)
    int am  = lane & 15;
    int ak8 = (lane >> 4) * 8;
    float4v acc0 = (float4v)(0.f), acc1 = (float4v)(0.f);
    #pragma unroll
    for (int kk = 0; kk < 4; ++kk) {
        int k0 = kk * 32 + ak8;
        half8 a  = *(const half8*)&Ah[am][k0];
        half8 b0 = *(const half8*)(Wt + (size_t)(wave * 32 + am) * DIM + k0);
        half8 b1 = *(const half8*)(Wt + (size_t)(wave * 32 + 16 + am) * DIM + k0);
        acc0 = __builtin_amdgcn_mfma_f32_16x16x32_f16(a, b0, acc0, 0, 0, 0);
        acc1 = __builtin_amdgcn_mfma_f32_16x16x32_f16(a, b1, acc1, 0, 0, 0);
    }
    __syncthreads();

    // epilogue: + win*b, relu, back to LDS fp16 for coalesced stores
    int q  = lane >> 4;
    int cc = lane & 15;
    {
        int col = wave * 32 + cc;
        float bv = bl[col];
        #pragma unroll
        for (int j = 0; j < 4; ++j) {
            int row = q * 4 + j;
            Ah[row][col] = __float2half(fmaxf(acc0[j] + winS[row] * bv, 0.f));
        }
        col = wave * 32 + 16 + cc;
        bv = bl[col];
        #pragma unroll
        for (int j = 0; j < 4; ++j) {
            int row = q * 4 + j;
            Ah[row][col] = __float2half(fmaxf(acc1[j] + winS[row] * bv, 0.f));
        }
    }
    __syncthreads();

    // 256 threads == 16 rows x 16 chunks
    int row = tid >> 4;
    int ch  = tid & 15;
    int gnode = blockIdx.x * 16 + row;
    half8 hv = *(const half8*)&Ah[row][ch * 8];
    size_t ro = (size_t)gnode * 16 + ch;

    if constexpr (!FINAL) {
        float f[8];
        #pragma unroll
        for (int t = 0; t < 8; ++t) f[t] = (float)hv[t];
        xout[ro] = f32x8_to_fp8(f);
    } else {
        float t0 = temp[0], t1 = temp[1], t2 = temp[2], t3 = temp[3], t4 = temp[4];
        uint2 u0 = x0h[ro], u1 = x1h[ro], u2 = x2h[ro], u3 = xin8[ro];
        float f0[8], f1[8], f2[8], f3[8];
        fp8x8_to_f32(u0, f0);
        fp8x8_to_f32(u1, f1);
        fp8x8_to_f32(u2, f2);
        fp8x8_to_f32(u3, f3);
        float out[8];
        #pragma unroll
        for (int t = 0; t < 8; ++t)
            out[t] = t0 * f0[t] + t1 * f1[t] + t2 * f2[t]
                   + t3 * f3[t] + t4 * (float)hv[t];
        size_t o = (size_t)gnode * DIM + ch * 8;
        *(float4*)(hidden + o)     = make_float4(out[0], out[1], out[2], out[3]);
        *(float4*)(hidden + o + 4) = make_float4(out[4], out[5], out[6], out[7]);
    }
}

extern "C" void kernel_launch(void* const* d_in, const int* in_sizes, int n_in,
                              void* d_out, int out_size, void* d_ws, size_t ws_size,
                              hipStream_t stream) {
    const float* x    = (const float*)d_in[0];
    const float* w    = (const float*)d_in[1];
    const int*   src  = (const int*)d_in[2];
    const int*   dst  = (const int*)d_in[3];
    const float* W    = (const float*)d_in[4];
    const float* b    = (const float*)d_in[5];
    const float* temp = (const float*)d_in[6];
    float* hidden = (float*)d_out;

    char* ws = (char*)d_ws;
    // 4 fp8 x buffers: init->X0, L1 X0->X1, L2 X1->X2, L3 X2->X3,
    // L4 gathers X3 and combines X0..X3 + its own output into hidden.
    uint2* X0 = (uint2*)ws;                  ws += (size_t)N_NODES * DIM;   // fp8: 1B/elem
    uint2* X1 = (uint2*)ws;                  ws += (size_t)N_NODES * DIM;
    uint2* X2 = (uint2*)ws;                  ws += (size_t)N_NODES * DIM;
    uint2* X3 = (uint2*)ws;                  ws += (size_t)N_NODES * DIM;
    __half* Wt = (__half*)ws;                ws += (size_t)LAYERS * DIM * DIM * sizeof(__half);
    int* cnt = (int*)ws;                     ws += (size_t)N_NODES * sizeof(int);
    int* edge_buf = (int*)ws;                ws += (size_t)(N_NODES * SLOT + 64) * sizeof(int);

    hipMemsetAsync(cnt, 0, (size_t)N_NODES * sizeof(int), stream);
    prep_kernel<<<BUCKET_BLOCKS + WT_BLOCKS + INIT_BLOCKS, 256, 0, stream>>>(
        src, dst, w, cnt, edge_buf, W, Wt, (const float4*)x, X0);

    const int layer_blocks = N_NODES / 16;   // 3125, exact
    layer_kernel<false><<<layer_blocks, 256, 0, stream>>>(
        X0, cnt, edge_buf, Wt + 0 * DIM * DIM, b + 0 * DIM,
        X1, hidden, temp, nullptr, nullptr, nullptr);
    layer_kernel<false><<<layer_blocks, 256, 0, stream>>>(
        X1, cnt, edge_buf, Wt + 1 * DIM * DIM, b + 1 * DIM,
        X2, hidden, temp, nullptr, nullptr, nullptr);
    layer_kernel<false><<<layer_blocks, 256, 0, stream>>>(
        X2, cnt, edge_buf, Wt + 2 * DIM * DIM, b + 2 * DIM,
        X3, hidden, temp, nullptr, nullptr, nullptr);
    layer_kernel<true><<<layer_blocks, 256, 0, stream>>>(
        X3, cnt, edge_buf, Wt + 3 * DIM * DIM, b + 3 * DIM,
        nullptr, hidden, temp, X0, X1, X2);
}